// Round 8
// baseline (213.176 us; speedup 1.0000x reference)
//
#include <hip/hip_runtime.h>
#include <hip/hip_bf16.h>

// Problem constants
#define M_DIM 2048
#define K_DIM 50000
#define N_DIM 256
#define L_PATH 32
// GEMM tiling: BM=64 so LDS/block = 80KB -> 2 blocks/CU (160KB = full LDS).
#define BMt 64
#define BNt 256
#define BKt 64
#define TOTAL_KSTEPS 782      // ceil(50000/64)
#define KSPLIT 16
#define STEPS_PER_SPLIT 49    // ceil(782/16)
#define MTILES 32             // 2048/64

typedef __bf16 bf16x8 __attribute__((ext_vector_type(8)));
typedef __bf16 bf16x4 __attribute__((ext_vector_type(4)));
typedef float f32x4 __attribute__((ext_vector_type(4)));
typedef float fx4 __attribute__((ext_vector_type(4)));

// x = A (2048x50000) * W^T (W is 256x50000), split-K. bf16 MFMA, fp32 acc.
// R7 structure (single 128-VGPR-safe stage set, counted-vmcnt, raw barrier)
// + 2 blocks/CU: R7 ran 1 block/CU so all 8 waves stalled in lockstep on the
// per-step HBM drain (~3600cyc) that compute (~700cyc) couldn't hide. A second
// resident block fills those stalls. BM 128->64: LDS 96->80KB (2x80=160=full),
// VGPR ~115<128 (no spill), grid 512 = 32 mtiles x 16 ksp.
__global__ __launch_bounds__(512)
void gemm_bf16_splitk(const float* __restrict__ A, const float* __restrict__ W,
                      float* __restrict__ outp, int use_atomic)
{
  // Swizzled bf16 LDS tiles: (row, col) at row*BKt + XOR on 8-col/16B granule
  __shared__ __align__(16) unsigned short sA[2][BMt * BKt];   // 2 x 8 KB
  __shared__ __align__(16) unsigned short sW[2][BNt * BKt];   // 2 x 32 KB

  // XCD swizzle (gridDim.x = 512): ksp = (bid&7)*2 + (bid>>8) -> all 32 blocks
  // of a ksp share one XCD; per-step W slab (64KB) stays L2-hot.
  int bid = blockIdx.x;
  int per = gridDim.x >> 3;
  int Lw = (bid & 7) * per + (bid >> 3);
  int mtile = Lw & (MTILES - 1);
  int ksp = Lw >> 5;                 // MTILES == 32

  int m0 = mtile * BMt;
  int s0 = ksp * STEPS_PER_SPLIT;
  int s1 = s0 + STEPS_PER_SPLIT;
  if (s1 > TOTAL_KSTEPS) s1 = TOTAL_KSTEPS;

  int tid = threadIdx.x;
  int wid = tid >> 6, lane = tid & 63;
  int wm = wid >> 2, wn = wid & 3;          // wave grid 2 x 4, each wave 32x64
  int l15 = lane & 15, l4 = lane >> 4;

  // Coalesced staging: 16 lanes x 16B cover one 64-col row chunk (256 B).
  int rowt = tid >> 4;   // 0..31
  int chk  = tid & 15;   // 16B chunk within row (4 fp32 cols)
  const float* Ab = A + (size_t)(m0 + rowt) * K_DIM + chk * 4;
  const float* Wb = W + (size_t)rowt * K_DIM + chk * 4;

  // LDS write offsets: cols [chk*4, chk*4+4) at swizzled granule
  int offA[2], offW[8];
#pragma unroll
  for (int i = 0; i < 2; ++i) {
    int r = i * 32 + rowt;
    offA[i] = r * BKt + ((((chk >> 1) ^ (r & 7)) << 3) + (chk & 1) * 4);
  }
#pragma unroll
  for (int i = 0; i < 8; ++i) {
    int r = i * 32 + rowt;
    offW[i] = r * BKt + ((((chk >> 1) ^ (r & 7)) << 3) + (chk & 1) * 4);
  }

  // SINGLE stage set: 10 x fx4 = 40 VGPR.
  fx4 ra[2], rw[8];

  auto issue = [&](int s) {
    size_t kb = (size_t)s * BKt;
    const float* ap = Ab + kb;
    const float* wp = Wb + kb;
    int k = s * BKt + chk * 4;
    if (k + 4 <= K_DIM) {
#pragma unroll
      for (int i = 0; i < 2; ++i) ra[i] = *reinterpret_cast<const fx4*>(ap + (size_t)i * 32 * K_DIM);
#pragma unroll
      for (int i = 0; i < 8; ++i) rw[i] = *reinterpret_cast<const fx4*>(wp + (size_t)i * 32 * K_DIM);
    } else {
#pragma unroll
      for (int i = 0; i < 2; ++i) {
        fx4 f;
#pragma unroll
        for (int e = 0; e < 4; ++e) f[e] = (k + e < K_DIM) ? ap[(size_t)i * 32 * K_DIM + e] : 0.f;
        ra[i] = f;
      }
#pragma unroll
      for (int i = 0; i < 8; ++i) {
        fx4 f;
#pragma unroll
        for (int e = 0; e < 4; ++e) f[e] = (k + e < K_DIM) ? wp[(size_t)i * 32 * K_DIM + e] : 0.f;
        rw[i] = f;
      }
    }
  };

  // fp32 -> bf16 casts (v_cvt_pk_bf16_f32, RTNE). Per-write counted vmcnt:
  // later-issued loads stay in flight.
  auto pack = [&](int p) {
#pragma unroll
    for (int i = 0; i < 2; ++i) {
      bf16x4 h;
      h[0] = (__bf16)ra[i][0]; h[1] = (__bf16)ra[i][1];
      h[2] = (__bf16)ra[i][2]; h[3] = (__bf16)ra[i][3];
      *reinterpret_cast<bf16x4*>(&sA[p][offA[i]]) = h;
    }
#pragma unroll
    for (int i = 0; i < 8; ++i) {
      bf16x4 h;
      h[0] = (__bf16)rw[i][0]; h[1] = (__bf16)rw[i][1];
      h[2] = (__bf16)rw[i][2]; h[3] = (__bf16)rw[i][3];
      *reinterpret_cast<bf16x4*>(&sW[p][offW[i]]) = h;
    }
  };

  f32x4 acc[2][4] = {};

  auto compute = [&](int p) {
#pragma unroll
    for (int kk = 0; kk < 2; ++kk) {
      bf16x8 afr[2], bfr[4];
      int c = kk * 32 + l4 * 8;
#pragma unroll
      for (int mf = 0; mf < 2; ++mf) {
        int r = wm * 32 + mf * 16 + l15;
        afr[mf] = *reinterpret_cast<const bf16x8*>(&sA[p][r * BKt + (c ^ ((r & 7) << 3))]);
      }
#pragma unroll
      for (int nf = 0; nf < 4; ++nf) {
        int r = wn * 64 + nf * 16 + l15;
        bfr[nf] = *reinterpret_cast<const bf16x8*>(&sW[p][r * BKt + (c ^ ((r & 7) << 3))]);
      }
#pragma unroll
      for (int mf = 0; mf < 2; ++mf)
#pragma unroll
        for (int nf = 0; nf < 4; ++nf)
          acc[mf][nf] = __builtin_amdgcn_mfma_f32_16x16x32_bf16(afr[mf], bfr[nf], acc[mf][nf], 0, 0, 0);
    }
  };

#define WB() do { asm volatile("s_waitcnt lgkmcnt(0)" ::: "memory"); \
                  __builtin_amdgcn_s_barrier(); } while (0)

  // Prologue: tile s0 staged to LDS[0]; tile s0+1's loads left in flight.
  issue(s0);
  pack(0);
  if (s0 + 1 < s1) issue(s0 + 1);
  WB();

  int p = 0;
  for (int t = s0; t < s1; ++t) {
    compute(p);                      // reads LDS[p]; in-flight loads drain behind
    if (t + 1 < s1) {
      pack(p ^ 1);                   // counted vmcnt: waits tile t+1 only
      if (t + 2 < s1) issue(t + 2);  // crosses the barrier in flight
      WB();
    }
    p ^= 1;
  }
#undef WB

  // epilogue: C/D layout col = lane&15, row = (lane>>4)*4 + j
  if (use_atomic) {
#pragma unroll
    for (int mf = 0; mf < 2; ++mf)
#pragma unroll
      for (int nf = 0; nf < 4; ++nf)
#pragma unroll
        for (int j = 0; j < 4; ++j) {
          int row = m0 + wm * 32 + mf * 16 + l4 * 4 + j;
          int col = wn * 64 + nf * 16 + l15;
          atomicAdd(&outp[(size_t)row * N_DIM + col], acc[mf][nf][j]);
        }
  } else {
    float* part = outp + (size_t)ksp * (M_DIM * N_DIM);
#pragma unroll
    for (int mf = 0; mf < 2; ++mf)
#pragma unroll
      for (int nf = 0; nf < 4; ++nf)
#pragma unroll
        for (int j = 0; j < 4; ++j) {
          int row = m0 + wm * 32 + mf * 16 + l4 * 4 + j;
          int col = wn * 64 + nf * 16 + l15;
          part[(size_t)row * N_DIM + col] = acc[mf][nf][j];
        }
  }
}

// One block (256 thr = 4 waves) per sample: reduce split-K partials for this
// row into LDS, gather path vecs, dot with x, BCE, atomically accumulate the
// batch-mean into out[0] (out is memsetAsync'd to 0 beforehand).
__global__ __launch_bounds__(256)
void loss_kernel(const float* __restrict__ part, int nparts,
                 const float* __restrict__ cls_w,
                 const int* __restrict__ nodes, const int* __restrict__ codes,
                 const int* __restrict__ lens, float* __restrict__ out)
{
  int i = blockIdx.x;
  int tid = threadIdx.x;
  __shared__ float s_x[N_DIM];
  {
    float s = 0.f;
    for (int k = 0; k < nparts; ++k)
      s += part[(size_t)k * (M_DIM * N_DIM) + (size_t)i * N_DIM + tid];
    s_x[tid] = s;
  }
  __syncthreads();

  int wid = tid >> 6, lane = tid & 63;
  __shared__ float s_logit[L_PATH];
  fx4 xv = *reinterpret_cast<const fx4*>(&s_x[lane * 4]);
#pragma unroll
  for (int j = 0; j < 8; ++j) {
    int pos = wid * 8 + j;
    int node = nodes[i * L_PATH + pos];
    fx4 cv = *reinterpret_cast<const fx4*>(&cls_w[(size_t)node * N_DIM + lane * 4]);
    float d = xv[0] * cv[0] + xv[1] * cv[1] + xv[2] * cv[2] + xv[3] * cv[3];
#pragma unroll
    for (int s = 32; s > 0; s >>= 1) d += __shfl_xor(d, s);
    if (lane == 0) s_logit[pos] = d;
  }
  __syncthreads();
  if (wid == 0) {
    int len = lens[i];
    int lenc = len < 1 ? 1 : len;
    float v = 0.f;
    if (lane < L_PATH && lane < lenc) {
      float z = s_logit[lane];
      float y = (float)codes[i * L_PATH + lane];
      v = fmaxf(z, 0.f) - z * y + log1pf(expf(-fabsf(z)));
    }
#pragma unroll
    for (int s = 32; s > 0; s >>= 1) v += __shfl_xor(v, s);
    if (lane == 0) atomicAdd(out, v / (float)lenc * (1.0f / (float)M_DIM));
  }
}

extern "C" void kernel_launch(void* const* d_in, const int* in_sizes, int n_in,
                              void* d_out, int out_size, void* d_ws, size_t ws_size,
                              hipStream_t stream) {
  const float* A     = (const float*)d_in[0];   // inputs_vector [2048, 50000]
  const float* W     = (const float*)d_in[1];   // W [256, 50000]
  const float* cls_w = (const float*)d_in[2];   // [49999, 256]
  const int* nodes   = (const int*)d_in[3];     // [2048, 32]
  const int* codes   = (const int*)d_in[4];     // [2048, 32]
  const int* lens    = (const int*)d_in[5];     // [2048]
  float* out = (float*)d_out;

  char* ws = (char*)d_ws;
  const size_t XBYTES = (size_t)M_DIM * N_DIM * sizeof(float);   // 2 MB
  float* x        = (float*)(ws + (size_t)(64u << 10));          // 2 MB (atomic path)
  float* partials = (float*)(ws + (size_t)(4u << 20));           // KSPLIT * 2 MB

  int use_atomic = (ws_size < (size_t)(4u << 20) + (size_t)KSPLIT * XBYTES) ? 1 : 0;

  hipMemsetAsync(out, 0, sizeof(float) * out_size, stream);
  if (use_atomic) {
    hipMemsetAsync(x, 0, XBYTES, stream);
    gemm_bf16_splitk<<<dim3(MTILES * KSPLIT), dim3(512), 0, stream>>>(A, W, x, 1);
    loss_kernel<<<dim3(M_DIM), dim3(256), 0, stream>>>(x, 1, cls_w, nodes, codes, lens, out);
  } else {
    gemm_bf16_splitk<<<dim3(MTILES * KSPLIT), dim3(512), 0, stream>>>(A, W, partials, 0);
    loss_kernel<<<dim3(M_DIM), dim3(256), 0, stream>>>(partials, KSPLIT, cls_w, nodes, codes, lens, out);
  }
}

// Round 9
// 178.225 us; speedup vs baseline: 1.1961x; 1.1961x over previous
//
#include <hip/hip_runtime.h>
#include <hip/hip_bf16.h>

// Problem constants
#define M_DIM 2048
#define K_DIM 50000
#define N_DIM 256
#define L_PATH 32
// GEMM tiling
#define BMt 128
#define BNt 256
#define BKt 64
#define TOTAL_KSTEPS 782      // ceil(50000/64)
#define KSPLIT 16
#define STEPS_PER_SPLIT 49    // ceil(782/16)
#define MTILES 16             // 2048/128
#define WTILE_SHORTS (BNt * BKt)   // 16384 shorts = 32KB per W step-tile

typedef __bf16 bf16x8 __attribute__((ext_vector_type(8)));
typedef __bf16 bf16x4 __attribute__((ext_vector_type(4)));
typedef __bf16 bf16x2 __attribute__((ext_vector_type(2)));
typedef float f32x4 __attribute__((ext_vector_type(4)));
typedef float fx4 __attribute__((ext_vector_type(4)));

#define GLL(g, l) __builtin_amdgcn_global_load_lds(                        \
    (const __attribute__((address_space(1))) void*)(g),                    \
    (__attribute__((address_space(3))) void*)(l), 16, 0, 0)

// ---------------------------------------------------------------------------
// Prepass: convert W (256 x 50000 fp32) to bf16 tiles in the EXACT swizzled
// LDS image: wsz[s][r*64 + (g^(r&7))*8 + e], zero-padded at the K tail.
// One block per step s; wave handles 2 rows/iter (lanes: 32 per row, 2 bf16
// per lane -> 256B coalesced reads, 128B packed writes).
__global__ __launch_bounds__(256)
void conv_w(const float* __restrict__ W, unsigned short* __restrict__ wsz)
{
  int s = blockIdx.x;
  int tid = threadIdx.x;
  int w = tid >> 6, lane = tid & 63;
  int rl = lane >> 5;              // which of the 2 rows
  int l31 = lane & 31;
  int g = l31 >> 2, e2 = l31 & 3;  // granule, bf16-pair within granule
  int kk = s * BKt + g * 8 + e2 * 2;
  unsigned short* outs = wsz + (size_t)s * WTILE_SHORTS;
#pragma unroll 4
  for (int i = 0; i < 32; ++i) {
    int r = i * 8 + w * 2 + rl;
    bf16x2 hh;
    if (kk + 2 <= K_DIM) {
      const float* p = W + (size_t)r * K_DIM + kk;
      hh[0] = (__bf16)p[0]; hh[1] = (__bf16)p[1];
    } else {
      hh[0] = (__bf16)0.f; hh[1] = (__bf16)0.f;
    }
    *reinterpret_cast<bf16x2*>(&outs[r * 64 + ((g ^ (r & 7)) * 8) + e2 * 2]) = hh;
  }
}

// ---------------------------------------------------------------------------
// x = A (2048x50000) * W^T, split-K=16. A: reg-staged fp32->bf16 (R7 proven,
// single stage set, fits the 128-VGPR cap). W: pre-converted bf16 streamed
// via global_load_lds into a triple-buffered LDS ring (no VGPR round trip,
// no cvt, no ds_write). Counted vmcnt(8) before compute: W(t+1)+A(t+1) stay
// in flight across the raw barrier; never drains to 0 in the loop.
__global__ __launch_bounds__(512)
void gemm_wpre(const float* __restrict__ A, const unsigned short* __restrict__ wsz,
               float* __restrict__ outp, int use_atomic)
{
  __shared__ __align__(16) unsigned short sA[2][BMt * BKt];     // 2 x 16 KB
  __shared__ __align__(16) unsigned short sW[3][WTILE_SHORTS];  // 3 x 32 KB

  // XCD swizzle: XCD x hosts ksp {2x,2x+1}; per-step W tile (32KB) L2-hot.
  int bid = blockIdx.x;
  int per = gridDim.x >> 3;
  int Lw = (bid & 7) * per + (bid >> 3);
  int mtile = Lw & (MTILES - 1);
  int ksp = Lw >> 4;

  int m0 = mtile * BMt;
  int s0 = ksp * STEPS_PER_SPLIT;
  int s1 = s0 + STEPS_PER_SPLIT;
  if (s1 > TOTAL_KSTEPS) s1 = TOTAL_KSTEPS;

  int tid = threadIdx.x;
  int wid = tid >> 6, lane = tid & 63;
  int wm = wid >> 2, wn = wid & 3;          // wave grid 2 x 4, each wave 64x64
  int l15 = lane & 15, l4 = lane >> 4;

  // A staging (R7 geometry): 16 lanes x 16B cover one 64-col row chunk.
  int rowt = tid >> 4;   // 0..31
  int chk  = tid & 15;
  const float* Ab = A + (size_t)(m0 + rowt) * K_DIM + chk * 4;
  int offA[4];
#pragma unroll
  for (int i = 0; i < 4; ++i) {
    int r = i * 32 + rowt;
    offA[i] = r * BKt + ((((chk >> 1) ^ (r & 7)) << 3) + (chk & 1) * 4);
  }
  fx4 ra[4];

  auto issueA = [&](int s) {
    size_t kb = (size_t)s * BKt;
    const float* ap = Ab + kb;
    if (s != TOTAL_KSTEPS - 1) {
#pragma unroll
      for (int i = 0; i < 4; ++i) ra[i] = *reinterpret_cast<const fx4*>(ap + (size_t)i * 32 * K_DIM);
    } else {
      int k = s * BKt + chk * 4;
#pragma unroll
      for (int i = 0; i < 4; ++i) {
        fx4 f;
#pragma unroll
        for (int e = 0; e < 4; ++e) f[e] = (k + e < K_DIM) ? ap[(size_t)i * 32 * K_DIM + e] : 0.f;
        ra[i] = f;
      }
    }
  };

  auto packA = [&](int p) {
#pragma unroll
    for (int i = 0; i < 4; ++i) {
      bf16x4 h;
      h[0] = (__bf16)ra[i][0]; h[1] = (__bf16)ra[i][1];
      h[2] = (__bf16)ra[i][2]; h[3] = (__bf16)ra[i][3];
      *reinterpret_cast<bf16x4*>(&sA[p][offA[i]]) = h;
    }
  };

  // W streaming: 4 GLL calls/wave/tile, 1KB each. Dest = wave-uniform base
  // (+ lane*16B by HW); src = identical offset in the pre-swizzled image.
  const unsigned short* Wsrc = wsz + wid * 2048 + lane * 8;
  auto gllW = [&](int t, int b) {
    const unsigned short* src = Wsrc + (size_t)t * WTILE_SHORTS;
    unsigned short* dst = &sW[b][wid * 2048];
#pragma unroll
    for (int c = 0; c < 4; ++c)
      GLL(src + c * 512, dst + c * 512);
  };

  f32x4 acc[4][4] = {};

  auto compute = [&](int pc, int bw) {
#pragma unroll
    for (int kk = 0; kk < 2; ++kk) {
      bf16x8 afr[4], bfr[4];
      int c = kk * 32 + l4 * 8;
#pragma unroll
      for (int mf = 0; mf < 4; ++mf) {
        int r = wm * 64 + mf * 16 + l15;
        afr[mf] = *reinterpret_cast<const bf16x8*>(&sA[pc][r * BKt + (c ^ ((r & 7) << 3))]);
      }
#pragma unroll
      for (int nf = 0; nf < 4; ++nf) {
        int r = wn * 64 + nf * 16 + l15;
        bfr[nf] = *reinterpret_cast<const bf16x8*>(&sW[bw][r * BKt + (c ^ ((r & 7) << 3))]);
      }
#pragma unroll
      for (int mf = 0; mf < 4; ++mf)
#pragma unroll
        for (int nf = 0; nf < 4; ++nf)
          acc[mf][nf] = __builtin_amdgcn_mfma_f32_16x16x32_bf16(afr[mf], bfr[nf], acc[mf][nf], 0, 0, 0);
    }
  };

  // Prologue: A(s0)+W(s0) issued; A packed; A(s0+1)+W(s0+1) left in flight.
  issueA(s0);
  gllW(s0, 0);
  packA(0);                       // counted vmcnt: waits A(s0) only
  issueA(s0 + 1);
  gllW(s0 + 1, 1);
  asm volatile("s_waitcnt lgkmcnt(0)" ::: "memory");
  __builtin_amdgcn_s_barrier();

  int t = s0;
  for (; t < s1 - 1; ++t) {
    int pc = (t - s0) & 1;
    int bw = (t - s0) % 3;
    // Retires W(t) (oldest); leaves A(t+1)+W(t+1) (8 newest) in flight.
    asm volatile("s_waitcnt vmcnt(8)" ::: "memory");
    compute(pc, bw);
    packA(pc ^ 1);                 // counted vmcnt: waits A(t+1), W(t+1) stays
    if (t + 2 < s1) {
      issueA(t + 2);
      gllW(t + 2, (t - s0 + 2) % 3);
    }
    asm volatile("s_waitcnt lgkmcnt(0)" ::: "memory");
    __builtin_amdgcn_s_barrier();
  }
  asm volatile("s_waitcnt vmcnt(0)" ::: "memory");
  compute((t - s0) & 1, (t - s0) % 3);

  // epilogue: C/D layout col = lane&15, row = (lane>>4)*4 + j
  if (use_atomic) {
#pragma unroll
    for (int mf = 0; mf < 4; ++mf)
#pragma unroll
      for (int nf = 0; nf < 4; ++nf)
#pragma unroll
        for (int j = 0; j < 4; ++j) {
          int row = m0 + wm * 64 + mf * 16 + l4 * 4 + j;
          int col = wn * 64 + nf * 16 + l15;
          atomicAdd(&outp[(size_t)row * N_DIM + col], acc[mf][nf][j]);
        }
  } else {
    float* part = outp + (size_t)ksp * (M_DIM * N_DIM);
#pragma unroll
    for (int mf = 0; mf < 4; ++mf)
#pragma unroll
      for (int nf = 0; nf < 4; ++nf)
#pragma unroll
        for (int j = 0; j < 4; ++j) {
          int row = m0 + wm * 64 + mf * 16 + l4 * 4 + j;
          int col = wn * 64 + nf * 16 + l15;
          part[(size_t)row * N_DIM + col] = acc[mf][nf][j];
        }
  }
}

// ---------------------------------------------------------------------------
// Legacy R7 GEMM (fp32 W staged through regs) -- fallback if ws is too small
// for the preconverted W image. Atomic epilogue only.
__global__ __launch_bounds__(512)
void gemm_legacy(const float* __restrict__ A, const float* __restrict__ W,
                 float* __restrict__ outp)
{
  __shared__ __align__(16) unsigned short sA[2][BMt * BKt];
  __shared__ __align__(16) unsigned short sW[2][BNt * BKt];
  int bid = blockIdx.x;
  int per = gridDim.x >> 3;
  int Lw = (bid & 7) * per + (bid >> 3);
  int mtile = Lw & (MTILES - 1);
  int ksp = Lw >> 4;
  int m0 = mtile * BMt;
  int s0 = ksp * STEPS_PER_SPLIT;
  int s1 = s0 + STEPS_PER_SPLIT;
  if (s1 > TOTAL_KSTEPS) s1 = TOTAL_KSTEPS;
  int tid = threadIdx.x;
  int wid = tid >> 6, lane = tid & 63;
  int wm = wid >> 2, wn = wid & 3;
  int l15 = lane & 15, l4 = lane >> 4;
  int rowt = tid >> 4, chk = tid & 15;
  const float* Ab = A + (size_t)(m0 + rowt) * K_DIM + chk * 4;
  const float* Wb = W + (size_t)rowt * K_DIM + chk * 4;
  int offA[4], offW[8];
#pragma unroll
  for (int i = 0; i < 4; ++i) {
    int r = i * 32 + rowt;
    offA[i] = r * BKt + ((((chk >> 1) ^ (r & 7)) << 3) + (chk & 1) * 4);
  }
#pragma unroll
  for (int i = 0; i < 8; ++i) {
    int r = i * 32 + rowt;
    offW[i] = r * BKt + ((((chk >> 1) ^ (r & 7)) << 3) + (chk & 1) * 4);
  }
  fx4 ra[4], rw[8];
  auto issue = [&](int s) {
    size_t kb = (size_t)s * BKt;
    const float* ap = Ab + kb;
    const float* wp = Wb + kb;
    int k = s * BKt + chk * 4;
    if (k + 4 <= K_DIM) {
#pragma unroll
      for (int i = 0; i < 4; ++i) ra[i] = *reinterpret_cast<const fx4*>(ap + (size_t)i * 32 * K_DIM);
#pragma unroll
      for (int i = 0; i < 8; ++i) rw[i] = *reinterpret_cast<const fx4*>(wp + (size_t)i * 32 * K_DIM);
    } else {
#pragma unroll
      for (int i = 0; i < 4; ++i) {
        fx4 f;
#pragma unroll
        for (int e = 0; e < 4; ++e) f[e] = (k + e < K_DIM) ? ap[(size_t)i * 32 * K_DIM + e] : 0.f;
        ra[i] = f;
      }
#pragma unroll
      for (int i = 0; i < 8; ++i) {
        fx4 f;
#pragma unroll
        for (int e = 0; e < 4; ++e) f[e] = (k + e < K_DIM) ? wp[(size_t)i * 32 * K_DIM + e] : 0.f;
        rw[i] = f;
      }
    }
  };
  auto pack = [&](int p) {
#pragma unroll
    for (int i = 0; i < 4; ++i) {
      bf16x4 h;
      h[0] = (__bf16)ra[i][0]; h[1] = (__bf16)ra[i][1];
      h[2] = (__bf16)ra[i][2]; h[3] = (__bf16)ra[i][3];
      *reinterpret_cast<bf16x4*>(&sA[p][offA[i]]) = h;
    }
#pragma unroll
    for (int i = 0; i < 8; ++i) {
      bf16x4 h;
      h[0] = (__bf16)rw[i][0]; h[1] = (__bf16)rw[i][1];
      h[2] = (__bf16)rw[i][2]; h[3] = (__bf16)rw[i][3];
      *reinterpret_cast<bf16x4*>(&sW[p][offW[i]]) = h;
    }
  };
  f32x4 acc[4][4] = {};
  auto compute = [&](int p) {
#pragma unroll
    for (int kk = 0; kk < 2; ++kk) {
      bf16x8 afr[4], bfr[4];
      int c = kk * 32 + l4 * 8;
#pragma unroll
      for (int mf = 0; mf < 4; ++mf) {
        int r = wm * 64 + mf * 16 + l15;
        afr[mf] = *reinterpret_cast<const bf16x8*>(&sA[p][r * BKt + (c ^ ((r & 7) << 3))]);
      }
#pragma unroll
      for (int nf = 0; nf < 4; ++nf) {
        int r = wn * 64 + nf * 16 + l15;
        bfr[nf] = *reinterpret_cast<const bf16x8*>(&sW[p][r * BKt + (c ^ ((r & 7) << 3))]);
      }
#pragma unroll
      for (int mf = 0; mf < 4; ++mf)
#pragma unroll
        for (int nf = 0; nf < 4; ++nf)
          acc[mf][nf] = __builtin_amdgcn_mfma_f32_16x16x32_bf16(afr[mf], bfr[nf], acc[mf][nf], 0, 0, 0);
    }
  };
#define WB() do { asm volatile("s_waitcnt lgkmcnt(0)" ::: "memory"); \
                  __builtin_amdgcn_s_barrier(); } while (0)
  issue(s0);
  pack(0);
  if (s0 + 1 < s1) issue(s0 + 1);
  WB();
  int p = 0;
  for (int t = s0; t < s1; ++t) {
    compute(p);
    if (t + 1 < s1) {
      pack(p ^ 1);
      if (t + 2 < s1) issue(t + 2);
      WB();
    }
    p ^= 1;
  }
#undef WB
#pragma unroll
  for (int mf = 0; mf < 4; ++mf)
#pragma unroll
    for (int nf = 0; nf < 4; ++nf)
#pragma unroll
      for (int j = 0; j < 4; ++j) {
        int row = m0 + wm * 64 + mf * 16 + l4 * 4 + j;
        int col = wn * 64 + nf * 16 + l15;
        atomicAdd(&outp[(size_t)row * N_DIM + col], acc[mf][nf][j]);
      }
}

// ---------------------------------------------------------------------------
// One block per sample: reduce split-K partials, gather path vecs, dot, BCE,
// atomically accumulate batch mean into out[0] (memset to 0 beforehand).
__global__ __launch_bounds__(256)
void loss_kernel(const float* __restrict__ part, int nparts,
                 const float* __restrict__ cls_w,
                 const int* __restrict__ nodes, const int* __restrict__ codes,
                 const int* __restrict__ lens, float* __restrict__ out)
{
  int i = blockIdx.x;
  int tid = threadIdx.x;
  __shared__ float s_x[N_DIM];
  {
    float s = 0.f;
    for (int k = 0; k < nparts; ++k)
      s += part[(size_t)k * (M_DIM * N_DIM) + (size_t)i * N_DIM + tid];
    s_x[tid] = s;
  }
  __syncthreads();

  int wid = tid >> 6, lane = tid & 63;
  __shared__ float s_logit[L_PATH];
  fx4 xv = *reinterpret_cast<const fx4*>(&s_x[lane * 4]);
#pragma unroll
  for (int j = 0; j < 8; ++j) {
    int pos = wid * 8 + j;
    int node = nodes[i * L_PATH + pos];
    fx4 cv = *reinterpret_cast<const fx4*>(&cls_w[(size_t)node * N_DIM + lane * 4]);
    float d = xv[0] * cv[0] + xv[1] * cv[1] + xv[2] * cv[2] + xv[3] * cv[3];
#pragma unroll
    for (int s = 32; s > 0; s >>= 1) d += __shfl_xor(d, s);
    if (lane == 0) s_logit[pos] = d;
  }
  __syncthreads();
  if (wid == 0) {
    int len = lens[i];
    int lenc = len < 1 ? 1 : len;
    float v = 0.f;
    if (lane < L_PATH && lane < lenc) {
      float z = s_logit[lane];
      float y = (float)codes[i * L_PATH + lane];
      v = fmaxf(z, 0.f) - z * y + log1pf(expf(-fabsf(z)));
    }
#pragma unroll
    for (int s = 32; s > 0; s >>= 1) v += __shfl_xor(v, s);
    if (lane == 0) atomicAdd(out, v / (float)lenc * (1.0f / (float)M_DIM));
  }
}

extern "C" void kernel_launch(void* const* d_in, const int* in_sizes, int n_in,
                              void* d_out, int out_size, void* d_ws, size_t ws_size,
                              hipStream_t stream) {
  const float* A     = (const float*)d_in[0];   // inputs_vector [2048, 50000]
  const float* W     = (const float*)d_in[1];   // W [256, 50000]
  const float* cls_w = (const float*)d_in[2];   // [49999, 256]
  const int* nodes   = (const int*)d_in[3];     // [2048, 32]
  const int* codes   = (const int*)d_in[4];     // [2048, 32]
  const int* lens    = (const int*)d_in[5];     // [2048]
  float* out = (float*)d_out;

  char* ws = (char*)d_ws;
  const size_t XBYTES  = (size_t)M_DIM * N_DIM * sizeof(float);              // 2 MB
  const size_t WSZB    = (size_t)TOTAL_KSTEPS * WTILE_SHORTS * 2;            // ~25.6 MB
  const size_t OFF_WSZ = (size_t)(4u << 20);
  const size_t OFF_PRT = (size_t)(32u << 20);
  float*          x        = (float*)(ws + (size_t)(64u << 10));
  unsigned short* wsz      = (unsigned short*)(ws + OFF_WSZ);
  float*          partials = (float*)(ws + OFF_PRT);

  const size_t need_full = OFF_PRT + (size_t)KSPLIT * XBYTES;   // 64 MB
  const size_t need_mid  = OFF_WSZ + WSZB;                      // ~29.6 MB

  hipMemsetAsync(out, 0, sizeof(float) * out_size, stream);
  if (ws_size >= need_full) {
    conv_w<<<dim3(TOTAL_KSTEPS), dim3(256), 0, stream>>>(W, wsz);
    gemm_wpre<<<dim3(MTILES * KSPLIT), dim3(512), 0, stream>>>(A, wsz, partials, 0);
    loss_kernel<<<dim3(M_DIM), dim3(256), 0, stream>>>(partials, KSPLIT, cls_w, nodes, codes, lens, out);
  } else if (ws_size >= need_mid) {
    hipMemsetAsync(x, 0, XBYTES, stream);
    conv_w<<<dim3(TOTAL_KSTEPS), dim3(256), 0, stream>>>(W, wsz);
    gemm_wpre<<<dim3(MTILES * KSPLIT), dim3(512), 0, stream>>>(A, wsz, x, 1);
    loss_kernel<<<dim3(M_DIM), dim3(256), 0, stream>>>(x, 1, cls_w, nodes, codes, lens, out);
  } else {
    hipMemsetAsync(x, 0, XBYTES, stream);
    gemm_legacy<<<dim3(MTILES * KSPLIT), dim3(512), 0, stream>>>(A, W, x);
    loss_kernel<<<dim3(M_DIM), dim3(256), 0, stream>>>(x, 1, cls_w, nodes, codes, lens, out);
  }
}